// Round 14
// baseline (455.867 us; speedup 1.0000x reference)
//
#include <hip/hip_runtime.h>
#include <hip/hip_cooperative_groups.h>

namespace cg = cooperative_groups;

// Problem constants (from reference)
#define V_ 12
#define N_ 80000
#define C_ 256
#define H_ 128
#define W_ 128
#define G_ 4096
#define M_ 512
#define E_ 200000
#define L_ 20
#define HD 128            // C/2 hidden dim
#define NROW (V_ * H_)    // row-buckets: (v, y) ; 1536
#define RCAP 128          // max items per row-bucket (Binomial λ=32; P(>128) ~ 0)
#define PCAP 32           // max pairs per point (Poisson λ=2.5; P(>=32) ~ 1e-19)
#define GSEG (G_ * 16)    // build: 16-lane segment per group (12 active)
#define QCH 64            // channels per gather block (quarter of C)
#define GATHER_VB (NROW * 4)             // 6144 gather virtual blocks
#define PAIR_VB ((E_ + 255) / 256)       // 782 pair-index virtual blocks
#define TOTAL_VB (GATHER_VB + PAIR_VB)
#define MLP_VB ((N_ + 11) / 12)          // 6667 mlp virtual blocks
#define NZERO (M_ * C_ + M_ + NROW + N_) // zero region: msum|mcnt|rcount|pcount
#define GRID 768                         // 3 blocks/CU co-resident (LDS allows 4)
#define BLK 256

// ---------------------------------------------------------------------------
// ONE cooperative kernel = the whole pipeline. Rationale: r8-r13 accounting
// only closes with ~10us per kernel-node overhead on this harness; fusing 5
// nodes into 1 with grid.sync() phase barriers removes 4 node boundaries.
__global__ void __launch_bounds__(BLK, 3)
fused_kernel(const float* __restrict__ img,
             const float* __restrict__ is_seen,
             const float* __restrict__ W1,
             const float* __restrict__ b1,
             const float* __restrict__ W2,
             const float* __restrict__ b2,
             const int* __restrict__ coords,
             const int* __restrict__ centers,
             const int* __restrict__ g2m,
             const int* __restrict__ pair_mask,
             const int* __restrict__ pair_point,
             float* __restrict__ out,
             float* __restrict__ msum,
             float* __restrict__ mcnt,
             int* __restrict__ rcount,
             int* __restrict__ pcount,
             float* __restrict__ mW1,
             float* __restrict__ rscale,
             int* __restrict__ rmeta,
             int* __restrict__ pitems) {
  cg::grid_group grid = cg::this_grid();
  __shared__ float smem[QCH * 129];       // 33KB; aliased per phase
  int bid = blockIdx.x;
  int t = threadIdx.x;
  int gtid = bid * BLK + t;

  // ---- Phase 1: zero accumulators/counters (msum..pcount contiguous) ----
  {
    float4* z = (float4*)msum;
    if (gtid < NZERO / 4) z[gtid] = make_float4(0.f, 0.f, 0.f, 0.f);
  }
  grid.sync();

  // ---- Phase 2: build both inverted indexes ----
  for (int idx = gtid; idx < GSEG + E_; idx += GRID * BLK) {
    if (idx < GSEG) {
      int g = idx >> 4;        // group
      int s = idx & 15;        // segment lane; s<12 = view
      int n = centers[g];      // broadcast
      float w = 0.f;
      int x = 0, y = 0;
      if (s < V_) {
        w = is_seen[(size_t)s * N_ + n];
        int2 xy = ((const int2*)coords)[(size_t)s * N_ + n];
        x = xy.x; y = xy.y;
      }
      float wsum = w;
      wsum += __shfl_xor(wsum, 1, 16);
      wsum += __shfl_xor(wsum, 2, 16);
      wsum += __shfl_xor(wsum, 4, 16);
      wsum += __shfl_xor(wsum, 8, 16);
      int m = g2m[g];          // broadcast
      if (s == 0) atomicAdd(&mcnt[m], 1.0f);
      if (s < V_) {
        float sc = w / (wsum + 1e-6f);
        int b = (s << 7) | y;
        int slot = atomicAdd(&rcount[b], 1);
        if (slot < RCAP) {
          rmeta[b * RCAP + slot] = m | (x << 9);  // m:9 bits, x:7 bits
          rscale[b * RCAP + slot] = sc;
        }
      }
    } else {
      int e = idx - GSEG;
      int p = pair_point[e];
      int slot = atomicAdd(&pcount[p], 1);
      if (slot < PCAP) pitems[(size_t)p * PCAP + slot] = pair_mask[e];
    }
  }
  grid.sync();

  // ---- Phase 3: row-bucket gather (coalesced loads, atomic msum) ----
  for (int vb = bid; vb < TOTAL_VB; vb += GRID) {
    if (vb >= GATHER_VB) {               // leftover pair blocks: none (handled
      break;                             // in phase 2); kept for vb layout
    }
    int b = vb >> 2;           // row-bucket (v,y)
    int cg_ = vb & 3;          // channel quarter
    int cnt = rcount[b];
    if (cnt == 0) continue;    // block-uniform
    if (cnt > RCAP) cnt = RCAP;
    int v = b >> 7;
    int y = b & 127;
    __syncthreads();           // protect smem from previous iteration readers
    const float4* base = (const float4*)(img +
        (((size_t)v * C_ + cg_ * QCH) * H_ + y) * W_);
#pragma unroll
    for (int i = 0; i < 8; ++i) {
      int f4 = i * 256 + t;    // flat float4 index over the 64x32 f4 slab
      int ch = f4 >> 5;
      int xo4 = f4 & 31;
      float4 u = base[(size_t)ch * (H_ * W_ / 4) + xo4];
      float* dst = &smem[ch * 129 + xo4 * 4];
      dst[0] = u.x; dst[1] = u.y; dst[2] = u.z; dst[3] = u.w;
    }
    __syncthreads();
    int w = t >> 6;
    int lane = t & 63;
    for (int it = w; it < cnt; it += 4) {
      int meta = rmeta[b * RCAP + it];
      float s = rscale[b * RCAP + it];
      int m = meta & 511;
      int x = (meta >> 9) & 127;
      float val = smem[lane * 129 + x] * s;   // Δ129 -> conflict-free
      atomicAdd(&msum[(size_t)m * C_ + cg_ * QCH + lane], val);
    }
  }
  grid.sync();

  // ---- Phase 4: mW1 = normalize(msum) @ W1 (512 blocks, t<128 active) ----
  if (bid < M_) {
    float* row = smem;         // 256 floats
    if (t < HD) {
      row[t] = msum[(size_t)bid * C_ + t];
      row[t + HD] = msum[(size_t)bid * C_ + t + HD];
    }
    __syncthreads();
    if (t < HD) {
      float cv = mcnt[bid];
      float inv = cv > 0.f ? 1.0f / fmaxf(cv, 1.0f) : 0.f;
      float acc = 0.f;
      for (int c = 0; c < C_; ++c) acc += row[c] * W1[(size_t)c * HD + t];
      mW1[(size_t)bid * HD + t] = acc * inv;
    }
  }
  grid.sync();

  // ---- Phase 5: point MLP (W2 staged ONCE per block for ~9 vblocks) ----
  {
    float* w2s = smem;                   // 2560 floats
    float* hl = smem + HD * L_;          // 4*3*130 = 1560 floats
    for (int i = t; i < HD * L_; i += BLK) w2s[i] = W2[i];
    int wave = t >> 6;
    int lane = t & 63;
    for (int pb = bid; pb < MLP_VB; pb += GRID) {
      int pbase = pb * 12 + wave * 3;
      __syncthreads();                   // w2s ready / previous hl consumed
#pragma unroll
      for (int pt = 0; pt < 3; ++pt) {
        int p = pbase + pt;
        if (p < N_) {
          int cnt = pcount[p];
          int k = cnt < PCAP ? cnt : PCAP;
          const int* lst = &pitems[(size_t)p * PCAP];
          float hx = 0.f, hy = 0.f;
          for (int it = 0; it < k; ++it) {
            int m = lst[it];
            float2 r = ((const float2*)(mW1 + (size_t)m * HD))[lane];
            hx += r.x;
            hy += r.y;
          }
          float invc = 1.0f / fmaxf((float)cnt, 1e-6f);
          hl[(wave * 3 + pt) * 130 + 2 * lane] =
              fmaxf(hx * invc + b1[2 * lane], 0.f);
          hl[(wave * 3 + pt) * 130 + 2 * lane + 1] =
              fmaxf(hy * invc + b1[2 * lane + 1], 0.f);
        }
      }
      __syncthreads();
      if (lane < 60) {
        int pt = lane / 20;
        int j = lane - pt * 20;
        int p = pbase + pt;
        if (p < N_) {
          float o = b2[j];
          const float* hrow = &hl[(wave * 3 + pt) * 130];
#pragma unroll 8
          for (int kk = 0; kk < HD; ++kk) o += hrow[kk] * w2s[kk * L_ + j];
          out[(size_t)p * L_ + j] = o;
        }
      }
    }
  }
}

// ---------------------------------------------------------------------------
extern "C" void kernel_launch(void* const* d_in, const int* in_sizes, int n_in,
                              void* d_out, int out_size, void* d_ws, size_t ws_size,
                              hipStream_t stream) {
  const float* img      = (const float*)d_in[0];
  const float* is_seen  = (const float*)d_in[1];
  const float* W1       = (const float*)d_in[2];
  const float* b1       = (const float*)d_in[3];
  const float* W2       = (const float*)d_in[4];
  const float* b2       = (const float*)d_in[5];
  const int* coords     = (const int*)d_in[6];
  const int* centers    = (const int*)d_in[7];
  const int* g2m        = (const int*)d_in[8];
  const int* pair_mask  = (const int*)d_in[9];
  const int* pair_point = (const int*)d_in[10];
  float* out = (float*)d_out;

  // Workspace layout — zero-init region FIRST and contiguous:
  //   msum[M*C] | mcnt[M] | rcount[NROW] | pcount[N]   <- zeroed in phase 1
  //   mW1[M*HD] | rscale[NROW*RCAP] | rmeta[NROW*RCAP] | pitems[N*PCAP]
  float* ws     = (float*)d_ws;
  float* msum   = ws;
  float* mcnt   = msum + (size_t)M_ * C_;
  int*   rcount = (int*)(mcnt + M_);
  int*   pcount = rcount + NROW;
  float* mW1    = (float*)(pcount + N_);
  float* rscale = mW1 + (size_t)M_ * HD;
  int*   rmeta  = (int*)(rscale + (size_t)NROW * RCAP);
  int*   pitems = rmeta + (size_t)NROW * RCAP;

  void* args[] = {
      (void*)&img, (void*)&is_seen, (void*)&W1, (void*)&b1, (void*)&W2,
      (void*)&b2, (void*)&coords, (void*)&centers, (void*)&g2m,
      (void*)&pair_mask, (void*)&pair_point, (void*)&out,
      (void*)&msum, (void*)&mcnt, (void*)&rcount, (void*)&pcount,
      (void*)&mW1, (void*)&rscale, (void*)&rmeta, (void*)&pitems};

  hipLaunchCooperativeKernel((void*)fused_kernel, dim3(GRID), dim3(BLK),
                             args, 0, stream);
}

// Round 15
// 276.208 us; speedup vs baseline: 1.6504x; 1.6504x over previous
//
#include <hip/hip_runtime.h>

// Problem constants (from reference)
#define V_ 12
#define N_ 80000
#define C_ 256
#define H_ 128
#define W_ 128
#define G_ 4096
#define M_ 512
#define E_ 200000
#define L_ 20
#define HD 128            // C/2 hidden dim
#define NROW (V_ * H_)    // row-buckets: (v, y) ; 1536
#define RCAP 128          // max items per row-bucket (Binomial λ=32; P(>128) ~ 0)
#define PCAP 32           // max pairs per point (Poisson λ=2.5; P(>=32) ~ 1e-19)
#define GV (G_ * V_)
#define GSEG (G_ * 16)    // build: 16-lane segment per group (12 active)
#define QCH 64            // channels per gather block (quarter of C)
// Zero-init region: msum[M*C] + mcnt[M] + rcount[NROW] + pcount[N] (contiguous)
#define NZERO (M_ * C_ + M_ + NROW + N_)   // 213,120 words (mult of 4)

// ---------------------------------------------------------------------------
// Kernel 0: zero the accumulator/counter region with plain stores.
__global__ void init_kernel(float4* __restrict__ z) {
  int i = blockIdx.x * blockDim.x + threadIdx.x;
  if (i < NZERO / 4) z[i] = make_float4(0.f, 0.f, 0.f, 0.f);
}

// ---------------------------------------------------------------------------
// Kernel 1: build both inverted indexes (segment-parallel group half + pair
// half). Exactly r12's form.
__global__ void build_kernel(const float* __restrict__ is_seen,
                             const int* __restrict__ coords,
                             const int* __restrict__ centers,
                             const int* __restrict__ g2m,
                             const int* __restrict__ pair_mask,
                             const int* __restrict__ pair_point,
                             int* __restrict__ rcount,
                             int* __restrict__ rmeta,
                             float* __restrict__ rscale,
                             int* __restrict__ pcount,
                             int* __restrict__ pitems,
                             float* __restrict__ mcnt) {
  int t = blockIdx.x * blockDim.x + threadIdx.x;
  if (t < GSEG) {
    int g = t >> 4;          // group
    int s = t & 15;          // segment lane; s<12 = view id
    int n = centers[g];      // broadcast
    float w = 0.f;
    int x = 0, y = 0;
    if (s < V_) {
      w = is_seen[(size_t)s * N_ + n];
      int2 xy = ((const int2*)coords)[(size_t)s * N_ + n];
      x = xy.x; y = xy.y;
    }
    float wsum = w;
    wsum += __shfl_xor(wsum, 1, 16);
    wsum += __shfl_xor(wsum, 2, 16);
    wsum += __shfl_xor(wsum, 4, 16);
    wsum += __shfl_xor(wsum, 8, 16);
    if (s == 0) atomicAdd(&mcnt[g2m[g]], 1.0f);
    if (s < V_) {
      float sc = w / (wsum + 1e-6f);
      int b = (s << 7) | y;
      int slot = atomicAdd(&rcount[b], 1);
      if (slot < RCAP) {
        rmeta[b * RCAP + slot] = g | (x << 12);  // g:12 bits, x:7 bits
        rscale[b * RCAP + slot] = sc;
      }
    }
  } else if (t < GSEG + E_) {
    int e = t - GSEG;
    int p = pair_point[e];
    int slot = atomicAdd(&pcount[p], 1);
    if (slot < PCAP) pitems[(size_t)p * PCAP + slot] = pair_mask[e];
  }
}

// ---------------------------------------------------------------------------
// Kernel 2: row-bucket gather, ATOMIC-FREE store form (measured 40.2us warm
// via the r10 duplicate probe).
__global__ void gather_kernel(const float* __restrict__ img,
                              const int* __restrict__ rcount,
                              const int* __restrict__ rmeta,
                              const float* __restrict__ rscale,
                              float* __restrict__ pvg) {
  int bid = blockIdx.x;
  int b = bid >> 2;            // row-bucket (v,y)
  int cg = bid & 3;            // channel quarter
  int cnt = rcount[b];
  if (cnt == 0) return;
  if (cnt > RCAP) cnt = RCAP;
  int v = b >> 7;
  int y = b & 127;
  int t = threadIdx.x;
  __shared__ float rows[QCH * 129];
  const float4* base = (const float4*)(img +
      (((size_t)v * C_ + cg * QCH) * H_ + y) * W_);
#pragma unroll
  for (int i = 0; i < 8; ++i) {
    int f4 = i * 256 + t;
    int ch = f4 >> 5;
    int xo4 = f4 & 31;
    float4 u = base[(size_t)ch * (H_ * W_ / 4) + xo4];
    float* dst = &rows[ch * 129 + xo4 * 4];
    dst[0] = u.x; dst[1] = u.y; dst[2] = u.z; dst[3] = u.w;
  }
  __syncthreads();
  int w = t >> 6;
  int lane = t & 63;
  for (int it = w; it < cnt; it += 4) {
    int meta = rmeta[b * RCAP + it];
    float s = rscale[b * RCAP + it];
    int g = meta & 4095;
    int x = (meta >> 12) & 127;
    float val = rows[lane * 129 + x] * s;
    pvg[((size_t)g * V_ + v) * C_ + cg * QCH + lane] = val;
  }
}

// ---------------------------------------------------------------------------
// Kernel 2b: per-group view reduction (1M coalesced atomics into msum).
__global__ void greduce_kernel(const float* __restrict__ pvg,
                               const int* __restrict__ g2m,
                               float* __restrict__ msum) {
  int g = blockIdx.x;
  int t = threadIdx.x;
  __shared__ float buf[V_ * C_];
  const float4* src = (const float4*)(pvg + (size_t)g * V_ * C_);
  float4* bf4 = (float4*)buf;
#pragma unroll
  for (int i = 0; i < 3; ++i) bf4[i * 256 + t] = src[i * 256 + t];
  __syncthreads();
  float s = 0.f;
#pragma unroll
  for (int v = 0; v < V_; ++v) s += buf[v * C_ + t];
  atomicAdd(&msum[(size_t)g2m[g] * C_ + t], s);
}

// ---------------------------------------------------------------------------
// Kernel 3: mW1 = normalize(msum) @ W1. IDEMPOTENT -> probe-duplicated x4.
__global__ void maskw1_kernel(const float* __restrict__ msum,
                              const float* __restrict__ mcnt,
                              const float* __restrict__ W1,
                              float* __restrict__ mW1) {
  int m = blockIdx.x;
  int j = threadIdx.x;
  __shared__ float row[C_];
  row[j] = msum[(size_t)m * C_ + j];
  row[j + HD] = msum[(size_t)m * C_ + j + HD];
  __syncthreads();
  float cv = mcnt[m];
  float inv = cv > 0.f ? 1.0f / fmaxf(cv, 1.0f) : 0.f;
  float acc = 0.f;
  for (int c = 0; c < C_; ++c) {
    acc += row[c] * W1[(size_t)c * HD + j];
  }
  mW1[(size_t)m * HD + j] = acc * inv;
}

// ---------------------------------------------------------------------------
// Kernel 4: point MLP (r12 LDS-W2 form). IDEMPOTENT -> probe-duplicated x4.
__global__ void point_mlp_kernel(const int* __restrict__ pcount,
                                 const int* __restrict__ pitems,
                                 const float* __restrict__ mW1,
                                 const float* __restrict__ b1,
                                 const float* __restrict__ W2,
                                 const float* __restrict__ b2,
                                 float* __restrict__ out) {
  __shared__ float w2s[HD * L_];
  __shared__ float hl[4][3][130];
  int t = threadIdx.x;
  for (int i = t; i < HD * L_; i += 256) w2s[i] = W2[i];
  __syncthreads();
  int wave = t >> 6;
  int lane = t & 63;
  int pbase = blockIdx.x * 12 + wave * 3;
#pragma unroll
  for (int pt = 0; pt < 3; ++pt) {
    int p = pbase + pt;
    if (p < N_) {
      int cnt = pcount[p];
      int k = cnt < PCAP ? cnt : PCAP;
      const int* lst = &pitems[(size_t)p * PCAP];
      float hx = 0.f, hy = 0.f;
      for (int it = 0; it < k; ++it) {
        int m = lst[it];
        float2 r = ((const float2*)(mW1 + (size_t)m * HD))[lane];
        hx += r.x;
        hy += r.y;
      }
      float invc = 1.0f / fmaxf((float)cnt, 1e-6f);
      hl[wave][pt][2 * lane]     = fmaxf(hx * invc + b1[2 * lane], 0.f);
      hl[wave][pt][2 * lane + 1] = fmaxf(hy * invc + b1[2 * lane + 1], 0.f);
    }
  }
  __syncthreads();
  if (lane < 60) {
    int pt = lane / 20;
    int j  = lane - pt * 20;
    int p = pbase + pt;
    if (p < N_) {
      float o = b2[j];
      const float* hrow = hl[wave][pt];
#pragma unroll 8
      for (int kk = 0; kk < HD; ++kk) o += hrow[kk] * w2s[kk * L_ + j];
      out[(size_t)p * L_ + j] = o;
    }
  }
}

// ---------------------------------------------------------------------------
extern "C" void kernel_launch(void* const* d_in, const int* in_sizes, int n_in,
                              void* d_out, int out_size, void* d_ws, size_t ws_size,
                              hipStream_t stream) {
  const float* img      = (const float*)d_in[0];
  const float* is_seen  = (const float*)d_in[1];
  const float* W1       = (const float*)d_in[2];
  const float* b1       = (const float*)d_in[3];
  const float* W2       = (const float*)d_in[4];
  const float* b2       = (const float*)d_in[5];
  const int* coords     = (const int*)d_in[6];
  const int* centers    = (const int*)d_in[7];
  const int* g2m        = (const int*)d_in[8];
  const int* pair_mask  = (const int*)d_in[9];
  const int* pair_point = (const int*)d_in[10];
  float* out = (float*)d_out;

  // Workspace layout — identical to r12:
  //   msum[M*C] | mcnt[M] | rcount[NROW] | pcount[N]   <- zeroed by init_kernel
  //   mW1[M*HD] | rscale[NROW*RCAP] | rmeta | pitems | pvg[GV*C]
  float* ws     = (float*)d_ws;
  float* msum   = ws;
  float* mcnt   = msum + (size_t)M_ * C_;
  int*   rcount = (int*)(mcnt + M_);
  int*   pcount = rcount + NROW;
  float* mW1    = (float*)(pcount + N_);
  float* rscale = mW1 + (size_t)M_ * HD;
  int*   rmeta  = (int*)(rscale + (size_t)NROW * RCAP);
  int*   pitems = rmeta + (size_t)NROW * RCAP;
  float* pvg    = (float*)(pitems + (size_t)N_ * PCAP);

  // ===== PROBE: r12 graph + 3x maskw1 + 3x point_mlp (both idempotent) =====
  // dur_us - 141.76 = 3*(maskw1 + point_mlp) + ~18us node overhead.
  init_kernel<<<(NZERO / 4 + 255) / 256, 256, 0, stream>>>((float4*)ws);
  build_kernel<<<(GSEG + E_ + 255) / 256, 256, 0, stream>>>(
      is_seen, coords, centers, g2m, pair_mask, pair_point,
      rcount, rmeta, rscale, pcount, pitems, mcnt);
  gather_kernel<<<NROW * 4, 256, 0, stream>>>(img, rcount, rmeta, rscale, pvg);
  greduce_kernel<<<G_, 256, 0, stream>>>(pvg, g2m, msum);
  maskw1_kernel<<<M_, HD, 0, stream>>>(msum, mcnt, W1, mW1);
  maskw1_kernel<<<M_, HD, 0, stream>>>(msum, mcnt, W1, mW1);
  maskw1_kernel<<<M_, HD, 0, stream>>>(msum, mcnt, W1, mW1);
  maskw1_kernel<<<M_, HD, 0, stream>>>(msum, mcnt, W1, mW1);
  point_mlp_kernel<<<(N_ + 11) / 12, 256, 0, stream>>>(
      pcount, pitems, mW1, b1, W2, b2, out);
  point_mlp_kernel<<<(N_ + 11) / 12, 256, 0, stream>>>(
      pcount, pitems, mW1, b1, W2, b2, out);
  point_mlp_kernel<<<(N_ + 11) / 12, 256, 0, stream>>>(
      pcount, pitems, mW1, b1, W2, b2, out);
  point_mlp_kernel<<<(N_ + 11) / 12, 256, 0, stream>>>(
      pcount, pitems, mW1, b1, W2, b2, out);
}

// Round 16
// 123.576 us; speedup vs baseline: 3.6890x; 2.2351x over previous
//
#include <hip/hip_runtime.h>

// Problem constants (from reference)
#define V_ 12
#define N_ 80000
#define C_ 256
#define H_ 128
#define W_ 128
#define G_ 4096
#define M_ 512
#define E_ 200000
#define L_ 20
#define HD 128            // C/2 hidden dim
#define NROW (V_ * H_)    // row-buckets: (v, y) ; 1536
#define RCAP 128          // max items per row-bucket (Binomial λ=32; P(>128) ~ 0)
#define PCAP 32           // max pairs per point (Poisson λ=2.5; P(>=32) ~ 1e-19)
#define GV (G_ * V_)
#define GSEG (G_ * 16)    // build: 16-lane segment per group (12 active)
#define QCH 64            // channels per gather block (quarter of C)
// Zero-init region: msum[M*C] + mcnt[M] + rcount[NROW] + pcount[N] (contiguous)
#define NZERO (M_ * C_ + M_ + NROW + N_)   // 213,120 words (mult of 4)

// ---------------------------------------------------------------------------
// Kernel 0: zero the accumulator/counter region with plain stores.
__global__ void init_kernel(float4* __restrict__ z) {
  int i = blockIdx.x * blockDim.x + threadIdx.x;
  if (i < NZERO / 4) z[i] = make_float4(0.f, 0.f, 0.f, 0.f);
}

// ---------------------------------------------------------------------------
// Kernel 1: build both inverted indexes (r12 form).
__global__ void build_kernel(const float* __restrict__ is_seen,
                             const int* __restrict__ coords,
                             const int* __restrict__ centers,
                             const int* __restrict__ g2m,
                             const int* __restrict__ pair_mask,
                             const int* __restrict__ pair_point,
                             int* __restrict__ rcount,
                             int* __restrict__ rmeta,
                             float* __restrict__ rscale,
                             int* __restrict__ pcount,
                             int* __restrict__ pitems,
                             float* __restrict__ mcnt) {
  int t = blockIdx.x * blockDim.x + threadIdx.x;
  if (t < GSEG) {
    int g = t >> 4;          // group
    int s = t & 15;          // segment lane; s<12 = view id
    int n = centers[g];      // broadcast
    float w = 0.f;
    int x = 0, y = 0;
    if (s < V_) {
      w = is_seen[(size_t)s * N_ + n];
      int2 xy = ((const int2*)coords)[(size_t)s * N_ + n];
      x = xy.x; y = xy.y;
    }
    float wsum = w;
    wsum += __shfl_xor(wsum, 1, 16);
    wsum += __shfl_xor(wsum, 2, 16);
    wsum += __shfl_xor(wsum, 4, 16);
    wsum += __shfl_xor(wsum, 8, 16);
    if (s == 0) atomicAdd(&mcnt[g2m[g]], 1.0f);
    if (s < V_) {
      float sc = w / (wsum + 1e-6f);
      int b = (s << 7) | y;
      int slot = atomicAdd(&rcount[b], 1);
      if (slot < RCAP) {
        rmeta[b * RCAP + slot] = g | (x << 12);  // g:12 bits, x:7 bits
        rscale[b * RCAP + slot] = sc;
      }
    }
  } else if (t < GSEG + E_) {
    int e = t - GSEG;
    int p = pair_point[e];
    int slot = atomicAdd(&pcount[p], 1);
    if (slot < PCAP) pitems[(size_t)p * PCAP + slot] = pair_mask[e];
  }
}

// ---------------------------------------------------------------------------
// Kernel 2: row-bucket gather, store form (measured 40.2us warm, r10 probe).
__global__ void gather_kernel(const float* __restrict__ img,
                              const int* __restrict__ rcount,
                              const int* __restrict__ rmeta,
                              const float* __restrict__ rscale,
                              float* __restrict__ pvg) {
  int bid = blockIdx.x;
  int b = bid >> 2;            // row-bucket (v,y)
  int cg = bid & 3;            // channel quarter
  int cnt = rcount[b];
  if (cnt == 0) return;
  if (cnt > RCAP) cnt = RCAP;
  int v = b >> 7;
  int y = b & 127;
  int t = threadIdx.x;
  __shared__ float rows[QCH * 129];
  const float4* base = (const float4*)(img +
      (((size_t)v * C_ + cg * QCH) * H_ + y) * W_);
#pragma unroll
  for (int i = 0; i < 8; ++i) {
    int f4 = i * 256 + t;
    int ch = f4 >> 5;
    int xo4 = f4 & 31;
    float4 u = base[(size_t)ch * (H_ * W_ / 4) + xo4];
    float* dst = &rows[ch * 129 + xo4 * 4];
    dst[0] = u.x; dst[1] = u.y; dst[2] = u.z; dst[3] = u.w;
  }
  __syncthreads();
  int w = t >> 6;
  int lane = t & 63;
  for (int it = w; it < cnt; it += 4) {
    int meta = rmeta[b * RCAP + it];
    float s = rscale[b * RCAP + it];
    int g = meta & 4095;
    int x = (meta >> 12) & 127;
    float val = rows[lane * 129 + x] * s;
    pvg[((size_t)g * V_ + v) * C_ + cg * QCH + lane] = val;
  }
}

// ---------------------------------------------------------------------------
// Kernel 2b: per-group view reduction (1M coalesced atomics into msum).
__global__ void greduce_kernel(const float* __restrict__ pvg,
                               const int* __restrict__ g2m,
                               float* __restrict__ msum) {
  int g = blockIdx.x;
  int t = threadIdx.x;
  __shared__ float buf[V_ * C_];
  const float4* src = (const float4*)(pvg + (size_t)g * V_ * C_);
  float4* bf4 = (float4*)buf;
#pragma unroll
  for (int i = 0; i < 3; ++i) bf4[i * 256 + t] = src[i * 256 + t];
  __syncthreads();
  float s = 0.f;
#pragma unroll
  for (int v = 0; v < V_; ++v) s += buf[v * C_ + t];
  atomicAdd(&msum[(size_t)g2m[g] * C_ + t], s);
}

// ---------------------------------------------------------------------------
// Kernel 3: mW1 = normalize(msum) @ W1 (r12 form; ~4.5us measured r15).
__global__ void maskw1_kernel(const float* __restrict__ msum,
                              const float* __restrict__ mcnt,
                              const float* __restrict__ W1,
                              float* __restrict__ mW1) {
  int m = blockIdx.x;
  int j = threadIdx.x;
  __shared__ float row[C_];
  row[j] = msum[(size_t)m * C_ + j];
  row[j + HD] = msum[(size_t)m * C_ + j + HD];
  __syncthreads();
  float cv = mcnt[m];
  float inv = cv > 0.f ? 1.0f / fmaxf(cv, 1.0f) : 0.f;
  float acc = 0.f;
  for (int c = 0; c < C_; ++c) {
    acc += row[c] * W1[(size_t)c * HD + j];
  }
  mW1[(size_t)m * HD + j] = acc * inv;
}

// ---------------------------------------------------------------------------
// Kernel 4: point MLP, VECTORIZED rewrite (r15 probe: old form = 34us, 4x its
// LDS-feed floor). Changes vs r12:
//  - W2 staged TRANSPOSED as w2t[j][kk] with 132-float rows (16B-aligned,
//    bank-group spread) -> phase 2 = 32 iters x 2 ds_read_b128 per lane
//    (was 128 x 2 ds_read_b32): 4x fewer LDS instructions.
//  - hl rows padded to 132 floats for aligned float4 reads.
//  - phase 1 reads first 4 mask ids as ONE int4 and issues up to 4
//    INDEPENDENT mW1 row loads (covers ~89% of points; scalar tail for k>4).
__global__ void point_mlp_kernel(const int* __restrict__ pcount,
                                 const int* __restrict__ pitems,
                                 const float* __restrict__ mW1,
                                 const float* __restrict__ b1,
                                 const float* __restrict__ W2,
                                 const float* __restrict__ b2,
                                 float* __restrict__ out) {
  __shared__ float w2t[L_][132];     // transposed W2: 20 x 132 = 10.3 KB
  __shared__ float hl[4][3][132];    // per-wave per-point hidden, 16B rows
  int t = threadIdx.x;
  for (int i = t; i < HD * L_; i += 256) {
    int kk = i / L_;
    int j = i - kk * L_;
    w2t[j][kk] = W2[i];
  }
  __syncthreads();
  int wave = t >> 6;
  int lane = t & 63;
  int pbase = blockIdx.x * 12 + wave * 3;
  float2 b1v = ((const float2*)b1)[lane];
#pragma unroll
  for (int pt = 0; pt < 3; ++pt) {
    int p = pbase + pt;
    if (p < N_) {
      int cnt = pcount[p];
      int k = cnt < PCAP ? cnt : PCAP;
      const int* lst = &pitems[(size_t)p * PCAP];
      int4 m4 = *(const int4*)lst;   // slots 0..3 (guarded below)
      float2 r0 = make_float2(0.f, 0.f), r1 = r0, r2 = r0, r3 = r0;
      if (k > 0) r0 = ((const float2*)(mW1 + (size_t)m4.x * HD))[lane];
      if (k > 1) r1 = ((const float2*)(mW1 + (size_t)m4.y * HD))[lane];
      if (k > 2) r2 = ((const float2*)(mW1 + (size_t)m4.z * HD))[lane];
      if (k > 3) r3 = ((const float2*)(mW1 + (size_t)m4.w * HD))[lane];
      float hx = r0.x + r1.x + r2.x + r3.x;
      float hy = r0.y + r1.y + r2.y + r3.y;
      for (int it = 4; it < k; ++it) {   // rare tail (P ~ 11%)
        int m = lst[it];
        float2 r = ((const float2*)(mW1 + (size_t)m * HD))[lane];
        hx += r.x;
        hy += r.y;
      }
      float invc = 1.0f / fmaxf((float)cnt, 1e-6f);
      hl[wave][pt][2 * lane]     = fmaxf(hx * invc + b1v.x, 0.f);
      hl[wave][pt][2 * lane + 1] = fmaxf(hy * invc + b1v.y, 0.f);
    }
  }
  __syncthreads();
  if (lane < 60) {
    int pt = lane / 20;
    int j  = lane - pt * 20;
    int p = pbase + pt;
    if (p < N_) {
      float o = b2[j];
      const float4* h4 = (const float4*)&hl[wave][pt][0];
      const float4* w4 = (const float4*)&w2t[j][0];
#pragma unroll
      for (int q = 0; q < HD / 4; ++q) {
        float4 hv = h4[q];
        float4 wv = w4[q];
        o += hv.x * wv.x + hv.y * wv.y + hv.z * wv.z + hv.w * wv.w;
      }
      out[(size_t)p * L_ + j] = o;
    }
  }
}

// ---------------------------------------------------------------------------
extern "C" void kernel_launch(void* const* d_in, const int* in_sizes, int n_in,
                              void* d_out, int out_size, void* d_ws, size_t ws_size,
                              hipStream_t stream) {
  const float* img      = (const float*)d_in[0];
  const float* is_seen  = (const float*)d_in[1];
  const float* W1       = (const float*)d_in[2];
  const float* b1       = (const float*)d_in[3];
  const float* W2       = (const float*)d_in[4];
  const float* b2       = (const float*)d_in[5];
  const int* coords     = (const int*)d_in[6];
  const int* centers    = (const int*)d_in[7];
  const int* g2m        = (const int*)d_in[8];
  const int* pair_mask  = (const int*)d_in[9];
  const int* pair_point = (const int*)d_in[10];
  float* out = (float*)d_out;

  // Workspace layout — identical to r12:
  //   msum[M*C] | mcnt[M] | rcount[NROW] | pcount[N]   <- zeroed by init_kernel
  //   mW1[M*HD] | rscale[NROW*RCAP] | rmeta | pitems | pvg[GV*C]
  float* ws     = (float*)d_ws;
  float* msum   = ws;
  float* mcnt   = msum + (size_t)M_ * C_;
  int*   rcount = (int*)(mcnt + M_);
  int*   pcount = rcount + NROW;
  float* mW1    = (float*)(pcount + N_);
  float* rscale = mW1 + (size_t)M_ * HD;
  int*   rmeta  = (int*)(rscale + (size_t)NROW * RCAP);
  int*   pitems = rmeta + (size_t)NROW * RCAP;
  float* pvg    = (float*)(pitems + (size_t)N_ * PCAP);

  init_kernel<<<(NZERO / 4 + 255) / 256, 256, 0, stream>>>((float4*)ws);
  build_kernel<<<(GSEG + E_ + 255) / 256, 256, 0, stream>>>(
      is_seen, coords, centers, g2m, pair_mask, pair_point,
      rcount, rmeta, rscale, pcount, pitems, mcnt);
  gather_kernel<<<NROW * 4, 256, 0, stream>>>(img, rcount, rmeta, rscale, pvg);
  greduce_kernel<<<G_, 256, 0, stream>>>(pvg, g2m, msum);
  maskw1_kernel<<<M_, HD, 0, stream>>>(msum, mcnt, W1, mW1);
  point_mlp_kernel<<<(N_ + 11) / 12, 256, 0, stream>>>(
      pcount, pitems, mW1, b1, W2, b2, out);
}